// Round 1
// baseline (1327.794 us; speedup 1.0000x reference)
//
#include <hip/hip_runtime.h>

// ---------------------------------------------------------------------------
// GIN 3-layer: h_{l+1} = act((h + agg(h)) @ W + b)
// Restructured: z = act(h) @ W ; a = b + z + agg(z)   (agg commutes with W)
// Intermediates z stored BF16; aggregation EDGE-PARALLEL into LDS fp32 via
// ds_add_f32 (divergence-free, chunked contiguous CSR ranges per block);
// GEMM = split-bf16 MFMA (hi*hi + hi*lo + lo*hi, fp32 acc) reading A from LDS.
// ---------------------------------------------------------------------------

typedef __attribute__((ext_vector_type(8))) short short8;
typedef __attribute__((ext_vector_type(4))) float f32x4;
typedef unsigned short ushort_t;
typedef unsigned int uint_t;

__device__ inline ushort_t bf16_rne(float f) {
  uint_t u = __float_as_uint(f);
  uint_t r = (u + 0x7FFFu + ((u >> 16) & 1u)) >> 16;
  return (ushort_t)r;
}
__device__ inline float bf16_to_f32(ushort_t h) {
  return __uint_as_float(((uint_t)h) << 16);
}

// ---- edge dtype detection: int64 (reference decl) vs int32 (JAX x64-off) ----
__global__ __launch_bounds__(256) void k_detect(const int* __restrict__ ew,
                                                int* __restrict__ flag, int E) {
  int i = blockIdx.x * 256 + threadIdx.x;
  int idx = 2 * i + 1;
  if (idx < 2 * E) {
    if (ew[idx] != 0) atomicOr(flag, 1);    // nonzero odd word => int32 layout
  }
}

// ---- CSR build (reads edges directly, no staging) ---------------------------
__global__ __launch_bounds__(256) void k_hist(const void* __restrict__ edges,
                                              const int* __restrict__ flag,
                                              int* __restrict__ counts, int E) {
  int e = blockIdx.x * 256 + threadIdx.x;
  if (e >= E) return;
  int d;
  if (*flag) d = ((const int*)edges)[E + e];
  else       d = (int)((const long long*)edges)[E + e];
  atomicAdd(&counts[d], 1);
}

__global__ __launch_bounds__(256) void k_scan1(const int* __restrict__ counts,
                                               int* __restrict__ offs,
                                               int* __restrict__ bsum, int N) {
  __shared__ int s[256];
  int t = threadIdx.x;
  int base = blockIdx.x * 1024 + t * 4;
  int c0 = 0, c1 = 0, c2 = 0, c3 = 0;
  if (base + 0 < N) c0 = counts[base + 0];
  if (base + 1 < N) c1 = counts[base + 1];
  if (base + 2 < N) c2 = counts[base + 2];
  if (base + 3 < N) c3 = counts[base + 3];
  int mySum = c0 + c1 + c2 + c3;
  s[t] = mySum;
  __syncthreads();
  for (int d = 1; d < 256; d <<= 1) {
    int v = (t >= d) ? s[t - d] : 0;
    __syncthreads();
    s[t] += v;
    __syncthreads();
  }
  int excl = s[t] - mySum;
  if (base + 0 < N) offs[base + 0] = excl;
  if (base + 1 < N) offs[base + 1] = excl + c0;
  if (base + 2 < N) offs[base + 2] = excl + c0 + c1;
  if (base + 3 < N) offs[base + 3] = excl + c0 + c1 + c2;
  if (t == 255) bsum[blockIdx.x] = s[255];
}

__global__ __launch_bounds__(128) void k_scan2(int* __restrict__ bsum, int nb) {
  __shared__ int s[128];
  int t = threadIdx.x;
  int v = (t < nb) ? bsum[t] : 0;
  s[t] = v;
  __syncthreads();
  for (int d = 1; d < 128; d <<= 1) {
    int u = (t >= d) ? s[t - d] : 0;
    __syncthreads();
    s[t] += u;
    __syncthreads();
  }
  if (t < nb) bsum[t] = s[t] - v;
}

__global__ __launch_bounds__(256) void k_scan3(int* __restrict__ offs,
                                               const int* __restrict__ bsum,
                                               int* __restrict__ cursor,
                                               int N, int E) {
  int t = threadIdx.x;
  int add = bsum[blockIdx.x];
  int base = blockIdx.x * 1024 + t * 4;
#pragma unroll
  for (int j = 0; j < 4; j++) {
    int i = base + j;
    if (i < N) { int v = offs[i] + add; offs[i] = v; cursor[i] = v; }
  }
  if (blockIdx.x == 0 && t == 0) offs[N] = E;
}

__global__ __launch_bounds__(256) void k_fill(const void* __restrict__ edges,
                                              const int* __restrict__ flag,
                                              int* __restrict__ cursor,
                                              int2* __restrict__ epair, int E) {
  int e = blockIdx.x * 256 + threadIdx.x;
  if (e >= E) return;
  int s, d;
  if (*flag) {
    const int* p = (const int*)edges;
    s = p[e]; d = p[E + e];
  } else {
    const long long* p = (const long long*)edges;
    s = (int)p[e]; d = (int)p[E + e];
  }
  int pos = atomicAdd(&cursor[d], 1);
  epair[pos] = make_int2(s, d);
}

// ---- W repack into MFMA B-fragment order (hi/lo split bf16) -----------------
__global__ __launch_bounds__(256) void k_repack(
    const float* __restrict__ W1, const float* __restrict__ W2,
    const float* __restrict__ W3,
    ushort_t* __restrict__ h1, ushort_t* __restrict__ l1,
    ushort_t* __restrict__ h2, ushort_t* __restrict__ l2,
    ushort_t* __restrict__ h3, ushort_t* __restrict__ l3) {
  int idx = blockIdx.x * 256 + threadIdx.x;
  const float* W; ushort_t* H; ushort_t* L; int NC; int i;
  if (idx < 16384)      { W = W1; H = h1; L = l1; NC = 128; i = idx; }
  else if (idx < 32768) { W = W2; H = h2; L = l2; NC = 128; i = idx - 16384; }
  else if (idx < 40960) { W = W3; H = h3; L = l3; NC = 64;  i = idx - 32768; }
  else return;
  int j = i & 7;
  int lane = (i >> 3) & 63;
  int NT = NC >> 4;
  int tile = (i >> 9) & (NT - 1);
  int ks = i >> (9 + (NC == 128 ? 3 : 2));
  int k = ks * 32 + (lane >> 4) * 8 + j;
  int n = tile * 16 + (lane & 15);
  float v = W[(size_t)k * NC + n];
  ushort_t hi = bf16_rne(v);
  ushort_t lo = bf16_rne(v - bf16_to_f32(hi));
  H[i] = hi; L[i] = lo;
}

// ---- layer 1 GEMM: Z(bf16)[M x NC] = A(fp32)[M x 128] @ W -------------------
template <int NC>
__global__ __launch_bounds__(256) void k_gemm_mfma(
    const float* __restrict__ A, const ushort_t* __restrict__ Bhi,
    const ushort_t* __restrict__ Blo, ushort_t* __restrict__ Z, int M) {
  constexpr int NT = NC / 16;
  int lane = threadIdx.x & 63;
  int wave = threadIdx.x >> 6;
  int row0 = blockIdx.x * 64 + wave * 16;
  int m = lane & 15;
  int q = lane >> 4;
  int grow = row0 + m;
  bool rowok = (grow < M);

  f32x4 acc[NT];
#pragma unroll
  for (int t = 0; t < NT; t++) { acc[t][0] = 0.f; acc[t][1] = 0.f; acc[t][2] = 0.f; acc[t][3] = 0.f; }

  const float* arow = A + (size_t)(rowok ? grow : 0) * 128 + q * 8;

#pragma unroll
  for (int ks = 0; ks < 4; ks++) {
    float av[8];
    *(float4*)(av)     = *(const float4*)(arow + ks * 32);
    *(float4*)(av + 4) = *(const float4*)(arow + ks * 32 + 4);
    short8 ahi, alo;
#pragma unroll
    for (int j = 0; j < 8; j++) {
      float v = av[j];
      ushort_t hi = bf16_rne(v);
      ahi[j] = (short)hi;
      alo[j] = (short)bf16_rne(v - bf16_to_f32(hi));
    }
#pragma unroll
    for (int t = 0; t < NT; t++) {
      const short8 bh = *(const short8*)(Bhi + (((size_t)ks * NT + t) * 64 + lane) * 8);
      const short8 bl = *(const short8*)(Blo + (((size_t)ks * NT + t) * 64 + lane) * 8);
      acc[t] = __builtin_amdgcn_mfma_f32_16x16x32_bf16(ahi, bh, acc[t], 0, 0, 0);
      acc[t] = __builtin_amdgcn_mfma_f32_16x16x32_bf16(ahi, bl, acc[t], 0, 0, 0);
      acc[t] = __builtin_amdgcn_mfma_f32_16x16x32_bf16(alo, bh, acc[t], 0, 0, 0);
    }
  }

  int zrow = row0 + q * 4;
#pragma unroll
  for (int r = 0; r < 4; r++) {
    if (zrow + r < M) {
#pragma unroll
      for (int t = 0; t < NT; t++)
        Z[(size_t)(zrow + r) * NC + t * 16 + m] = bf16_rne(acc[t][r]);
    }
  }
}

// ---- fused agg + GEMM (layers 2,3): edge-parallel LDS aggregation -----------
// Block owns 64 dst rows; its edges are the contiguous CSR range
// [offs[row0], offs[row0+rows]).  acc[64][130] fp32 in LDS, init b + z[own].
// Edge phase: 64 groups of 4 lanes, each group a contiguous edge chunk
// (uniform trip count, zero divergence); per edge each lane loads 64B of the
// gathered z row and ds_add_f32's 32 cols.  Pad S=130 keeps flush conflicts
// ~4-way (cheap) and rows 8B-aligned for ds_read_b64 in the MFMA phase.
template <int NC>
__global__ __launch_bounds__(256, 4) void k_fused(
    const ushort_t* __restrict__ Zin, const int2* __restrict__ ep,
    const int* __restrict__ offs, const float* __restrict__ bias,
    const ushort_t* __restrict__ Bhi, const ushort_t* __restrict__ Blo,
    ushort_t* __restrict__ Zout, int M) {
  constexpr int NT = NC / 16;
  constexpr int S = 130;
  __shared__ float sacc[64 * S];

  int t = threadIdx.x;
  int row0 = blockIdx.x * 64;
  int rows = min(64, M - row0);
  int r = t >> 2, sub = t & 3;

  // ---- init: sacc[r][c] = bias[c] + Zin[row0+r][c] ----
  {
    int grow = row0 + r;
    const ushort_t* zr = Zin + (size_t)(grow < M ? grow : 0) * 128 + sub * 8;
    const float* bq = bias + sub * 8;
    float* dst = sacc + r * S + sub * 8;
#pragma unroll
    for (int kk = 0; kk < 4; kk++) {
      short8 u = *(const short8*)(zr + kk * 32);
      float4 b0 = *(const float4*)(bq + kk * 32);
      float4 b1 = *(const float4*)(bq + kk * 32 + 4);
      float v[8];
      v[0] = b0.x + bf16_to_f32((ushort_t)u[0]);
      v[1] = b0.y + bf16_to_f32((ushort_t)u[1]);
      v[2] = b0.z + bf16_to_f32((ushort_t)u[2]);
      v[3] = b0.w + bf16_to_f32((ushort_t)u[3]);
      v[4] = b1.x + bf16_to_f32((ushort_t)u[4]);
      v[5] = b1.y + bf16_to_f32((ushort_t)u[5]);
      v[6] = b1.z + bf16_to_f32((ushort_t)u[6]);
      v[7] = b1.w + bf16_to_f32((ushort_t)u[7]);
#pragma unroll
      for (int jj = 0; jj < 8; jj += 2)
        *(float2*)(dst + kk * 32 + jj) = make_float2(v[jj], v[jj + 1]);
    }
  }
  __syncthreads();

  // ---- edge-parallel aggregation ----
  {
    int estart = offs[row0];
    int eend = offs[row0 + rows];
    int ne = eend - estart;
    int cs = (ne + 63) >> 6;                    // chunk per 4-lane group
    int g = t >> 2;
    int e = estart + g * cs;
    int ge = min(e + cs, eend);
    for (; e + 2 <= ge; e += 2) {
      int2 p0 = ep[e];
      int2 p1 = ep[e + 1];
      const ushort_t* za = Zin + (size_t)p0.x * 128 + sub * 8;
      const ushort_t* zb = Zin + (size_t)p1.x * 128 + sub * 8;
      short8 ua[4], ub[4];
#pragma unroll
      for (int kk = 0; kk < 4; kk++) ua[kk] = *(const short8*)(za + kk * 32);
#pragma unroll
      for (int kk = 0; kk < 4; kk++) ub[kk] = *(const short8*)(zb + kk * 32);
      float* d0 = sacc + (p0.y - row0) * S + sub * 8;
      float* d1 = sacc + (p1.y - row0) * S + sub * 8;
#pragma unroll
      for (int kk = 0; kk < 4; kk++)
#pragma unroll
        for (int jj = 0; jj < 8; jj++)
          atomicAdd(&d0[kk * 32 + jj], bf16_to_f32((ushort_t)ua[kk][jj]));
#pragma unroll
      for (int kk = 0; kk < 4; kk++)
#pragma unroll
        for (int jj = 0; jj < 8; jj++)
          atomicAdd(&d1[kk * 32 + jj], bf16_to_f32((ushort_t)ub[kk][jj]));
    }
    if (e < ge) {
      int2 p0 = ep[e];
      const ushort_t* za = Zin + (size_t)p0.x * 128 + sub * 8;
      float* d0 = sacc + (p0.y - row0) * S + sub * 8;
#pragma unroll
      for (int kk = 0; kk < 4; kk++) {
        short8 u = *(const short8*)(za + kk * 32);
#pragma unroll
        for (int jj = 0; jj < 8; jj++)
          atomicAdd(&d0[kk * 32 + jj], bf16_to_f32((ushort_t)u[jj]));
      }
    }
  }
  __syncthreads();

  // ---- relu + split-bf16 + MFMA, A from LDS ----
  int lane = t & 63;
  int wave = t >> 6;
  int m = lane & 15;
  int q = lane >> 4;
  const float* ar = sacc + (wave * 16 + m) * S + q * 8;

  f32x4 acc[NT];
#pragma unroll
  for (int tt = 0; tt < NT; tt++) { acc[tt][0] = 0.f; acc[tt][1] = 0.f; acc[tt][2] = 0.f; acc[tt][3] = 0.f; }

#pragma unroll
  for (int ks = 0; ks < 4; ks++) {
    short8 ahi, alo;
#pragma unroll
    for (int jj = 0; jj < 8; jj += 2) {
      float2 vv = *(const float2*)(ar + ks * 32 + jj);
      float v0 = fmaxf(vv.x, 0.f);
      float v1 = fmaxf(vv.y, 0.f);
      ushort_t h0 = bf16_rne(v0);
      ahi[jj] = (short)h0;
      alo[jj] = (short)bf16_rne(v0 - bf16_to_f32(h0));
      ushort_t h1 = bf16_rne(v1);
      ahi[jj + 1] = (short)h1;
      alo[jj + 1] = (short)bf16_rne(v1 - bf16_to_f32(h1));
    }
#pragma unroll
    for (int tt = 0; tt < NT; tt++) {
      const short8 bh = *(const short8*)(Bhi + (((size_t)ks * NT + tt) * 64 + lane) * 8);
      const short8 bl = *(const short8*)(Blo + (((size_t)ks * NT + tt) * 64 + lane) * 8);
      acc[tt] = __builtin_amdgcn_mfma_f32_16x16x32_bf16(ahi, bh, acc[tt], 0, 0, 0);
      acc[tt] = __builtin_amdgcn_mfma_f32_16x16x32_bf16(ahi, bl, acc[tt], 0, 0, 0);
      acc[tt] = __builtin_amdgcn_mfma_f32_16x16x32_bf16(alo, bh, acc[tt], 0, 0, 0);
    }
  }

  int zrow = row0 + wave * 16 + q * 4;
#pragma unroll
  for (int rr = 0; rr < 4; rr++) {
    if (zrow + rr < M) {
#pragma unroll
      for (int tt = 0; tt < NT; tt++)
        Zout[(size_t)(zrow + rr) * NC + tt * 16 + m] = bf16_rne(acc[tt][rr]);
    }
  }
}

// ---- final agg (64 cols): out = b + z + agg(z), edge-parallel LDS -----------
__global__ __launch_bounds__(256, 4) void k_agg64(const ushort_t* __restrict__ z,
                                                  const int2* __restrict__ ep,
                                                  const int* __restrict__ offs,
                                                  const float* __restrict__ bias,
                                                  float* __restrict__ out, int N) {
  constexpr int S = 66;
  __shared__ float sacc[64 * S];
  int t = threadIdx.x;
  int row0 = blockIdx.x * 64;
  int rows = min(64, N - row0);
  int r = t >> 2, sub = t & 3;

  {
    int grow = row0 + r;
    const ushort_t* zr = z + (size_t)(grow < N ? grow : 0) * 64 + sub * 8;
    const float* bq = bias + sub * 8;
    float* dst = sacc + r * S + sub * 8;
#pragma unroll
    for (int kk = 0; kk < 2; kk++) {
      short8 u = *(const short8*)(zr + kk * 32);
      float4 b0 = *(const float4*)(bq + kk * 32);
      float4 b1 = *(const float4*)(bq + kk * 32 + 4);
      float v[8];
      v[0] = b0.x + bf16_to_f32((ushort_t)u[0]);
      v[1] = b0.y + bf16_to_f32((ushort_t)u[1]);
      v[2] = b0.z + bf16_to_f32((ushort_t)u[2]);
      v[3] = b0.w + bf16_to_f32((ushort_t)u[3]);
      v[4] = b1.x + bf16_to_f32((ushort_t)u[4]);
      v[5] = b1.y + bf16_to_f32((ushort_t)u[5]);
      v[6] = b1.z + bf16_to_f32((ushort_t)u[6]);
      v[7] = b1.w + bf16_to_f32((ushort_t)u[7]);
#pragma unroll
      for (int jj = 0; jj < 8; jj += 2)
        *(float2*)(dst + kk * 32 + jj) = make_float2(v[jj], v[jj + 1]);
    }
  }
  __syncthreads();

  {
    int estart = offs[row0];
    int eend = offs[row0 + rows];
    int ne = eend - estart;
    int cs = (ne + 63) >> 6;
    int g = t >> 2;
    int e = estart + g * cs;
    int ge = min(e + cs, eend);
    for (; e + 2 <= ge; e += 2) {
      int2 p0 = ep[e];
      int2 p1 = ep[e + 1];
      const ushort_t* za = z + (size_t)p0.x * 64 + sub * 8;
      const ushort_t* zb = z + (size_t)p1.x * 64 + sub * 8;
      short8 ua[2], ub[2];
#pragma unroll
      for (int kk = 0; kk < 2; kk++) ua[kk] = *(const short8*)(za + kk * 32);
#pragma unroll
      for (int kk = 0; kk < 2; kk++) ub[kk] = *(const short8*)(zb + kk * 32);
      float* d0 = sacc + (p0.y - row0) * S + sub * 8;
      float* d1 = sacc + (p1.y - row0) * S + sub * 8;
#pragma unroll
      for (int kk = 0; kk < 2; kk++)
#pragma unroll
        for (int jj = 0; jj < 8; jj++)
          atomicAdd(&d0[kk * 32 + jj], bf16_to_f32((ushort_t)ua[kk][jj]));
#pragma unroll
      for (int kk = 0; kk < 2; kk++)
#pragma unroll
        for (int jj = 0; jj < 8; jj++)
          atomicAdd(&d1[kk * 32 + jj], bf16_to_f32((ushort_t)ub[kk][jj]));
    }
    if (e < ge) {
      int2 p0 = ep[e];
      const ushort_t* za = z + (size_t)p0.x * 64 + sub * 8;
      float* d0 = sacc + (p0.y - row0) * S + sub * 8;
#pragma unroll
      for (int kk = 0; kk < 2; kk++) {
        short8 u = *(const short8*)(za + kk * 32);
#pragma unroll
        for (int jj = 0; jj < 8; jj++)
          atomicAdd(&d0[kk * 32 + jj], bf16_to_f32((ushort_t)u[jj]));
      }
    }
  }
  __syncthreads();

  if (row0 + r < N) {
    float* op = out + (size_t)(row0 + r) * 64 + sub * 8;
    const float* sp = sacc + r * S + sub * 8;
#pragma unroll
    for (int kk = 0; kk < 2; kk++) {
      float4 o0 = make_float4(sp[kk * 32 + 0], sp[kk * 32 + 1], sp[kk * 32 + 2], sp[kk * 32 + 3]);
      float4 o1 = make_float4(sp[kk * 32 + 4], sp[kk * 32 + 5], sp[kk * 32 + 6], sp[kk * 32 + 7]);
      *(float4*)(op + kk * 32)     = o0;
      *(float4*)(op + kk * 32 + 4) = o1;
    }
  }
}

// ---------------------------------------------------------------------------
extern "C" void kernel_launch(void* const* d_in, const int* in_sizes, int n_in,
                              void* d_out, int out_size, void* d_ws, size_t ws_size,
                              hipStream_t stream) {
  const float* x  = (const float*)d_in[0];
  const void* edges = d_in[1];
  const float* W1 = (const float*)d_in[2];
  const float* b1 = (const float*)d_in[3];
  const float* W2 = (const float*)d_in[4];
  const float* b2 = (const float*)d_in[5];
  const float* W3 = (const float*)d_in[6];
  const float* b3 = (const float*)d_in[7];
  float* out = (float*)d_out;

  int N = in_sizes[0] / 128;   // 100000
  int E = in_sizes[1] / 2;     // 600000

  char* w = (char*)d_ws;
  size_t off = 0;
  auto alloc = [&](size_t bytes) -> void* {
    void* p = w + off;
    off = (off + bytes + 255) & ~(size_t)255;
    return p;
  };
  size_t curBytes = ((size_t)N * 4 + 255) & ~(size_t)255;
  int*   cursor = (int*)alloc(curBytes);     // degree counts, then fill cursor
  int*   flag   = (int*)alloc(4);            // adjacent: one memset covers both
  int2*  epair  = (int2*)alloc((size_t)E * 8);
  int*   offs   = (int*)alloc((size_t)(N + 1) * 4);
  int*   bsum   = (int*)alloc(4096);
  ushort_t* h1  = (ushort_t*)alloc(16384 * 2);
  ushort_t* l1  = (ushort_t*)alloc(16384 * 2);
  ushort_t* h2  = (ushort_t*)alloc(16384 * 2);
  ushort_t* l2  = (ushort_t*)alloc(16384 * 2);
  ushort_t* h3  = (ushort_t*)alloc(8192 * 2);
  ushort_t* l3  = (ushort_t*)alloc(8192 * 2);
  ushort_t* z1  = (ushort_t*)alloc((size_t)N * 128 * 2);  // bf16
  ushort_t* z2  = (ushort_t*)alloc((size_t)N * 128 * 2);  // bf16
  ushort_t* z3  = z1;                                     // reuse (N x 64 fits)

  int ge = (E + 255) / 256;
  int nb = (N + 1023) / 1024;

  hipMemsetAsync(cursor, 0, curBytes + 4, stream);
  k_detect<<<4, 256, 0, stream>>>((const int*)edges, flag, E);
  k_hist<<<ge, 256, 0, stream>>>(edges, flag, cursor, E);
  k_scan1<<<nb, 256, 0, stream>>>(cursor, offs, bsum, N);
  k_scan2<<<1, 128, 0, stream>>>(bsum, nb);
  k_scan3<<<nb, 256, 0, stream>>>(offs, bsum, cursor, N, E);
  k_fill<<<ge, 256, 0, stream>>>(edges, flag, cursor, epair, E);
  k_repack<<<160, 256, 0, stream>>>(W1, W2, W3, h1, l1, h2, l2, h3, l3);

  int gm = (N + 63) / 64;
  // layer 1: z1 = x @ W1   (bf16 out)
  k_gemm_mfma<128><<<gm, 256, 0, stream>>>(x, h1, l1, z1, N);
  // layer 2 fused: a1 = b1 + z1 + agg(z1) (LDS); z2 = relu(a1) @ W2
  k_fused<128><<<gm, 256, 0, stream>>>(z1, epair, offs, b1, h2, l2, z2, N);
  // layer 3 fused: a2 = b2 + z2 + agg(z2) (LDS); z3 = relu(a2) @ W3
  k_fused<64><<<gm, 256, 0, stream>>>(z2, epair, offs, b2, h3, l3, z3, N);
  // final agg: out = b3 + z3 + agg(z3)   (fp32 out)
  k_agg64<<<gm, 256, 0, stream>>>(z3, epair, offs, b3, out, N);
}

// Round 2
// 300.588 us; speedup vs baseline: 4.4173x; 4.4173x over previous
//
#include <hip/hip_runtime.h>

// ---------------------------------------------------------------------------
// GIN 3-layer: h_{l+1} = act((h + agg(h)) @ W + b)
// Restructured: z = act(h) @ W ; a = b + z + agg(z)   (agg commutes with W)
// Intermediates z stored BF16 (halves gather traffic); aggregation in fp32
// registers; GEMM = split-bf16 MFMA (hi*hi + hi*lo + lo*hi, fp32 acc).
// Layers 2,3 fused: gather directly into MFMA A-fragment registers.
// Round 2: edge loop unrolled x4 (16 outstanding 16B loads/lane) to deepen
// the memory pipeline; k_agg64 remainder gets a x2 step.
// (Round-1 LDS-atomic experiment reverted: per-element fp32 LDS atomics were
//  ~8x slower than register accumulation.)
// ---------------------------------------------------------------------------

typedef __attribute__((ext_vector_type(8))) short short8;
typedef __attribute__((ext_vector_type(4))) float f32x4;
typedef unsigned short ushort_t;
typedef unsigned int uint_t;

__device__ inline ushort_t bf16_rne(float f) {
  uint_t u = __float_as_uint(f);
  uint_t r = (u + 0x7FFFu + ((u >> 16) & 1u)) >> 16;
  return (ushort_t)r;
}
__device__ inline float bf16_to_f32(ushort_t h) {
  return __uint_as_float(((uint_t)h) << 16);
}

// ---- edge dtype detection: int64 (reference decl) vs int32 (JAX x64-off) ----
__global__ __launch_bounds__(256) void k_detect(const int* __restrict__ ew,
                                                int* __restrict__ flag, int E) {
  int i = blockIdx.x * 256 + threadIdx.x;
  int idx = 2 * i + 1;
  if (idx < 2 * E) {
    if (ew[idx] != 0) atomicOr(flag, 1);    // nonzero odd word => int32 layout
  }
}

// ---- CSR build (reads edges directly, no staging) ---------------------------
__global__ __launch_bounds__(256) void k_hist(const void* __restrict__ edges,
                                              const int* __restrict__ flag,
                                              int* __restrict__ counts, int E) {
  int e = blockIdx.x * 256 + threadIdx.x;
  if (e >= E) return;
  int d;
  if (*flag) d = ((const int*)edges)[E + e];
  else       d = (int)((const long long*)edges)[E + e];
  atomicAdd(&counts[d], 1);
}

__global__ __launch_bounds__(256) void k_scan1(const int* __restrict__ counts,
                                               int* __restrict__ offs,
                                               int* __restrict__ bsum, int N) {
  __shared__ int s[256];
  int t = threadIdx.x;
  int base = blockIdx.x * 1024 + t * 4;
  int c0 = 0, c1 = 0, c2 = 0, c3 = 0;
  if (base + 0 < N) c0 = counts[base + 0];
  if (base + 1 < N) c1 = counts[base + 1];
  if (base + 2 < N) c2 = counts[base + 2];
  if (base + 3 < N) c3 = counts[base + 3];
  int mySum = c0 + c1 + c2 + c3;
  s[t] = mySum;
  __syncthreads();
  for (int d = 1; d < 256; d <<= 1) {
    int v = (t >= d) ? s[t - d] : 0;
    __syncthreads();
    s[t] += v;
    __syncthreads();
  }
  int excl = s[t] - mySum;
  if (base + 0 < N) offs[base + 0] = excl;
  if (base + 1 < N) offs[base + 1] = excl + c0;
  if (base + 2 < N) offs[base + 2] = excl + c0 + c1;
  if (base + 3 < N) offs[base + 3] = excl + c0 + c1 + c2;
  if (t == 255) bsum[blockIdx.x] = s[255];
}

__global__ __launch_bounds__(128) void k_scan2(int* __restrict__ bsum, int nb) {
  __shared__ int s[128];
  int t = threadIdx.x;
  int v = (t < nb) ? bsum[t] : 0;
  s[t] = v;
  __syncthreads();
  for (int d = 1; d < 128; d <<= 1) {
    int u = (t >= d) ? s[t - d] : 0;
    __syncthreads();
    s[t] += u;
    __syncthreads();
  }
  if (t < nb) bsum[t] = s[t] - v;
}

__global__ __launch_bounds__(256) void k_scan3(int* __restrict__ offs,
                                               const int* __restrict__ bsum,
                                               int* __restrict__ cursor,
                                               int N, int E) {
  int t = threadIdx.x;
  int add = bsum[blockIdx.x];
  int base = blockIdx.x * 1024 + t * 4;
#pragma unroll
  for (int j = 0; j < 4; j++) {
    int i = base + j;
    if (i < N) { int v = offs[i] + add; offs[i] = v; cursor[i] = v; }
  }
  if (blockIdx.x == 0 && t == 0) offs[N] = E;
}

__global__ __launch_bounds__(256) void k_fill(const void* __restrict__ edges,
                                              const int* __restrict__ flag,
                                              int* __restrict__ cursor,
                                              int* __restrict__ csr, int E) {
  int e = blockIdx.x * 256 + threadIdx.x;
  if (e >= E) return;
  int s, d;
  if (*flag) {
    const int* p = (const int*)edges;
    s = p[e]; d = p[E + e];
  } else {
    const long long* p = (const long long*)edges;
    s = (int)p[e]; d = (int)p[E + e];
  }
  int pos = atomicAdd(&cursor[d], 1);
  csr[pos] = s;
}

// ---- W repack into MFMA B-fragment order (hi/lo split bf16) -----------------
__global__ __launch_bounds__(256) void k_repack(
    const float* __restrict__ W1, const float* __restrict__ W2,
    const float* __restrict__ W3,
    ushort_t* __restrict__ h1, ushort_t* __restrict__ l1,
    ushort_t* __restrict__ h2, ushort_t* __restrict__ l2,
    ushort_t* __restrict__ h3, ushort_t* __restrict__ l3) {
  int idx = blockIdx.x * 256 + threadIdx.x;
  const float* W; ushort_t* H; ushort_t* L; int NC; int i;
  if (idx < 16384)      { W = W1; H = h1; L = l1; NC = 128; i = idx; }
  else if (idx < 32768) { W = W2; H = h2; L = l2; NC = 128; i = idx - 16384; }
  else if (idx < 40960) { W = W3; H = h3; L = l3; NC = 64;  i = idx - 32768; }
  else return;
  int j = i & 7;
  int lane = (i >> 3) & 63;
  int NT = NC >> 4;
  int tile = (i >> 9) & (NT - 1);
  int ks = i >> (9 + (NC == 128 ? 3 : 2));
  int k = ks * 32 + (lane >> 4) * 8 + j;
  int n = tile * 16 + (lane & 15);
  float v = W[(size_t)k * NC + n];
  ushort_t hi = bf16_rne(v);
  ushort_t lo = bf16_rne(v - bf16_to_f32(hi));
  H[i] = hi; L[i] = lo;
}

// ---- layer 1 GEMM: Z(bf16)[M x NC] = A(fp32)[M x 128] @ W -------------------
template <int NC>
__global__ __launch_bounds__(256) void k_gemm_mfma(
    const float* __restrict__ A, const ushort_t* __restrict__ Bhi,
    const ushort_t* __restrict__ Blo, ushort_t* __restrict__ Z, int M) {
  constexpr int NT = NC / 16;
  int lane = threadIdx.x & 63;
  int wave = threadIdx.x >> 6;
  int row0 = blockIdx.x * 64 + wave * 16;
  int m = lane & 15;
  int q = lane >> 4;
  int grow = row0 + m;
  bool rowok = (grow < M);

  f32x4 acc[NT];
#pragma unroll
  for (int t = 0; t < NT; t++) { acc[t][0] = 0.f; acc[t][1] = 0.f; acc[t][2] = 0.f; acc[t][3] = 0.f; }

  const float* arow = A + (size_t)(rowok ? grow : 0) * 128 + q * 8;

#pragma unroll
  for (int ks = 0; ks < 4; ks++) {
    float av[8];
    *(float4*)(av)     = *(const float4*)(arow + ks * 32);
    *(float4*)(av + 4) = *(const float4*)(arow + ks * 32 + 4);
    short8 ahi, alo;
#pragma unroll
    for (int j = 0; j < 8; j++) {
      float v = av[j];
      ushort_t hi = bf16_rne(v);
      ahi[j] = (short)hi;
      alo[j] = (short)bf16_rne(v - bf16_to_f32(hi));
    }
#pragma unroll
    for (int t = 0; t < NT; t++) {
      const short8 bh = *(const short8*)(Bhi + (((size_t)ks * NT + t) * 64 + lane) * 8);
      const short8 bl = *(const short8*)(Blo + (((size_t)ks * NT + t) * 64 + lane) * 8);
      acc[t] = __builtin_amdgcn_mfma_f32_16x16x32_bf16(ahi, bh, acc[t], 0, 0, 0);
      acc[t] = __builtin_amdgcn_mfma_f32_16x16x32_bf16(ahi, bl, acc[t], 0, 0, 0);
      acc[t] = __builtin_amdgcn_mfma_f32_16x16x32_bf16(alo, bh, acc[t], 0, 0, 0);
    }
  }

  int zrow = row0 + q * 4;
#pragma unroll
  for (int r = 0; r < 4; r++) {
    if (zrow + r < M) {
#pragma unroll
      for (int t = 0; t < NT; t++)
        Z[(size_t)(zrow + r) * NC + t * 16 + m] = bf16_rne(acc[t][r]);
    }
  }
}

// ---- fused agg + GEMM (layers 2,3): bf16 z in, bf16 z out -------------------
// Lane (m, q) aggregates a[row][ks*32+q*8+j] in fp32 regs from bf16 z rows.
// Edge loop unrolled x4: 16 independent dwordx4 gathers issued before any
// accumulation (deep memory pipeline), then relu + hi/lo split + MFMA.
template <int NC>
__global__ __launch_bounds__(256, 4) void k_fused(
    const ushort_t* __restrict__ Zin, const int* __restrict__ csr,
    const int* __restrict__ offs, const float* __restrict__ bias,
    const ushort_t* __restrict__ Bhi, const ushort_t* __restrict__ Blo,
    ushort_t* __restrict__ Zout, int M) {
  constexpr int NT = NC / 16;
  int lane = threadIdx.x & 63;
  int wave = threadIdx.x >> 6;
  int row0 = blockIdx.x * 64 + wave * 16;
  int m = lane & 15;
  int q = lane >> 4;
  int grow = row0 + m;
  bool rowok = (grow < M);

  // accumulators a[grow][ks*32 + q*8 + j], init = bias + Zin[grow]
  float av[4][8];
  const ushort_t* zr0 = Zin + (size_t)(rowok ? grow : 0) * 128 + q * 8;
  const float* bq = bias + q * 8;
#pragma unroll
  for (int ks = 0; ks < 4; ks++) {
    float4 b0 = *(const float4*)(bq + ks * 32);
    float4 b1 = *(const float4*)(bq + ks * 32 + 4);
    short8 u = *(const short8*)(zr0 + ks * 32);
    av[ks][0] = b0.x + bf16_to_f32((ushort_t)u[0]);
    av[ks][1] = b0.y + bf16_to_f32((ushort_t)u[1]);
    av[ks][2] = b0.z + bf16_to_f32((ushort_t)u[2]);
    av[ks][3] = b0.w + bf16_to_f32((ushort_t)u[3]);
    av[ks][4] = b1.x + bf16_to_f32((ushort_t)u[4]);
    av[ks][5] = b1.y + bf16_to_f32((ushort_t)u[5]);
    av[ks][6] = b1.z + bf16_to_f32((ushort_t)u[6]);
    av[ks][7] = b1.w + bf16_to_f32((ushort_t)u[7]);
  }

  int s = 0, e = 0;
  if (rowok) { s = offs[grow]; e = offs[grow + 1]; }
  int j = s;
  // x4: issue 16 gather loads (4 rows x 4 chunks) before accumulating
  for (; j + 4 <= e; j += 4) {
    int i0 = csr[j], i1 = csr[j + 1], i2 = csr[j + 2], i3 = csr[j + 3];
    const ushort_t* za = Zin + (size_t)i0 * 128 + q * 8;
    const ushort_t* zb = Zin + (size_t)i1 * 128 + q * 8;
    const ushort_t* zc = Zin + (size_t)i2 * 128 + q * 8;
    const ushort_t* zd = Zin + (size_t)i3 * 128 + q * 8;
    short8 ua[4], ub[4], uc[4], ud[4];
#pragma unroll
    for (int ks = 0; ks < 4; ks++) ua[ks] = *(const short8*)(za + ks * 32);
#pragma unroll
    for (int ks = 0; ks < 4; ks++) ub[ks] = *(const short8*)(zb + ks * 32);
#pragma unroll
    for (int ks = 0; ks < 4; ks++) uc[ks] = *(const short8*)(zc + ks * 32);
#pragma unroll
    for (int ks = 0; ks < 4; ks++) ud[ks] = *(const short8*)(zd + ks * 32);
#pragma unroll
    for (int ks = 0; ks < 4; ks++)
#pragma unroll
      for (int jj = 0; jj < 8; jj++)
        av[ks][jj] += (bf16_to_f32((ushort_t)ua[ks][jj]) +
                       bf16_to_f32((ushort_t)ub[ks][jj])) +
                      (bf16_to_f32((ushort_t)uc[ks][jj]) +
                       bf16_to_f32((ushort_t)ud[ks][jj]));
  }
  if (j + 2 <= e) {
    int i0 = csr[j], i1 = csr[j + 1];
    j += 2;
    const ushort_t* za = Zin + (size_t)i0 * 128 + q * 8;
    const ushort_t* zb = Zin + (size_t)i1 * 128 + q * 8;
    short8 ua[4], ub[4];
#pragma unroll
    for (int ks = 0; ks < 4; ks++) ua[ks] = *(const short8*)(za + ks * 32);
#pragma unroll
    for (int ks = 0; ks < 4; ks++) ub[ks] = *(const short8*)(zb + ks * 32);
#pragma unroll
    for (int ks = 0; ks < 4; ks++)
#pragma unroll
      for (int jj = 0; jj < 8; jj++)
        av[ks][jj] += bf16_to_f32((ushort_t)ua[ks][jj]) +
                      bf16_to_f32((ushort_t)ub[ks][jj]);
  }
  if (j < e) {
    int i0 = csr[j];
    const ushort_t* za = Zin + (size_t)i0 * 128 + q * 8;
#pragma unroll
    for (int ks = 0; ks < 4; ks++) {
      short8 u = *(const short8*)(za + ks * 32);
#pragma unroll
      for (int jj = 0; jj < 8; jj++)
        av[ks][jj] += bf16_to_f32((ushort_t)u[jj]);
    }
  }

  // relu + split-bf16 + MFMA
  f32x4 acc[NT];
#pragma unroll
  for (int tt = 0; tt < NT; tt++) { acc[tt][0] = 0.f; acc[tt][1] = 0.f; acc[tt][2] = 0.f; acc[tt][3] = 0.f; }

#pragma unroll
  for (int ks = 0; ks < 4; ks++) {
    short8 ahi, alo;
#pragma unroll
    for (int jj = 0; jj < 8; jj++) {
      float v = fmaxf(av[ks][jj], 0.f);
      ushort_t hi = bf16_rne(v);
      ahi[jj] = (short)hi;
      alo[jj] = (short)bf16_rne(v - bf16_to_f32(hi));
    }
#pragma unroll
    for (int tt = 0; tt < NT; tt++) {
      const short8 bh = *(const short8*)(Bhi + (((size_t)ks * NT + tt) * 64 + lane) * 8);
      const short8 bl = *(const short8*)(Blo + (((size_t)ks * NT + tt) * 64 + lane) * 8);
      acc[tt] = __builtin_amdgcn_mfma_f32_16x16x32_bf16(ahi, bh, acc[tt], 0, 0, 0);
      acc[tt] = __builtin_amdgcn_mfma_f32_16x16x32_bf16(ahi, bl, acc[tt], 0, 0, 0);
      acc[tt] = __builtin_amdgcn_mfma_f32_16x16x32_bf16(alo, bh, acc[tt], 0, 0, 0);
    }
  }

  int zrow = row0 + q * 4;
#pragma unroll
  for (int r = 0; r < 4; r++) {
    if (zrow + r < M) {
#pragma unroll
      for (int tt = 0; tt < NT; tt++)
        Zout[(size_t)(zrow + r) * NC + tt * 16 + m] = bf16_rne(acc[tt][r]);
    }
  }
}

// ---- final agg (64 cols, bf16 z in, fp32 out): out = b + z + agg(z) ---------
// 8 lanes per node, 8 bf16 cols each (16B loads); edge loop unrolled x4,
// remainder via x2 then x1 to shorten the dependent tail.
__global__ __launch_bounds__(256) void k_agg64(const ushort_t* __restrict__ z,
                                               const int* __restrict__ csr,
                                               const int* __restrict__ offs,
                                               const float* __restrict__ bias,
                                               float* __restrict__ out, int N) {
  int t = threadIdx.x;
  int node = blockIdx.x * 32 + (t >> 3);
  if (node >= N) return;
  int c = (t & 7) * 8;
  float acc[8];
  {
    short8 u = *(const short8*)(z + (size_t)node * 64 + c);
#pragma unroll
    for (int jj = 0; jj < 8; jj++)
      acc[jj] = bias[c + jj] + bf16_to_f32((ushort_t)u[jj]);
  }
  int s = offs[node], e = offs[node + 1];
  int j = s;
  for (; j + 4 <= e; j += 4) {
    int i0 = csr[j], i1 = csr[j + 1], i2 = csr[j + 2], i3 = csr[j + 3];
    short8 u0 = *(const short8*)(z + (size_t)i0 * 64 + c);
    short8 u1 = *(const short8*)(z + (size_t)i1 * 64 + c);
    short8 u2 = *(const short8*)(z + (size_t)i2 * 64 + c);
    short8 u3 = *(const short8*)(z + (size_t)i3 * 64 + c);
#pragma unroll
    for (int jj = 0; jj < 8; jj++)
      acc[jj] += (bf16_to_f32((ushort_t)u0[jj]) + bf16_to_f32((ushort_t)u1[jj])) +
                 (bf16_to_f32((ushort_t)u2[jj]) + bf16_to_f32((ushort_t)u3[jj]));
  }
  if (j + 2 <= e) {
    int i0 = csr[j], i1 = csr[j + 1];
    j += 2;
    short8 u0 = *(const short8*)(z + (size_t)i0 * 64 + c);
    short8 u1 = *(const short8*)(z + (size_t)i1 * 64 + c);
#pragma unroll
    for (int jj = 0; jj < 8; jj++)
      acc[jj] += bf16_to_f32((ushort_t)u0[jj]) + bf16_to_f32((ushort_t)u1[jj]);
  }
  if (j < e) {
    int i0 = csr[j];
    short8 u = *(const short8*)(z + (size_t)i0 * 64 + c);
#pragma unroll
    for (int jj = 0; jj < 8; jj++)
      acc[jj] += bf16_to_f32((ushort_t)u[jj]);
  }
  float4 o0 = make_float4(acc[0], acc[1], acc[2], acc[3]);
  float4 o1 = make_float4(acc[4], acc[5], acc[6], acc[7]);
  *(float4*)&out[(size_t)node * 64 + c]     = o0;
  *(float4*)&out[(size_t)node * 64 + c + 4] = o1;
}

// ---------------------------------------------------------------------------
extern "C" void kernel_launch(void* const* d_in, const int* in_sizes, int n_in,
                              void* d_out, int out_size, void* d_ws, size_t ws_size,
                              hipStream_t stream) {
  const float* x  = (const float*)d_in[0];
  const void* edges = d_in[1];
  const float* W1 = (const float*)d_in[2];
  const float* b1 = (const float*)d_in[3];
  const float* W2 = (const float*)d_in[4];
  const float* b2 = (const float*)d_in[5];
  const float* W3 = (const float*)d_in[6];
  const float* b3 = (const float*)d_in[7];
  float* out = (float*)d_out;

  int N = in_sizes[0] / 128;   // 100000
  int E = in_sizes[1] / 2;     // 600000

  char* w = (char*)d_ws;
  size_t off = 0;
  auto alloc = [&](size_t bytes) -> void* {
    void* p = w + off;
    off = (off + bytes + 255) & ~(size_t)255;
    return p;
  };
  size_t curBytes = ((size_t)N * 4 + 255) & ~(size_t)255;
  int*   cursor = (int*)alloc(curBytes);     // degree counts, then fill cursor
  int*   flag   = (int*)alloc(4);            // adjacent: one memset covers both
  int*   csr    = (int*)alloc((size_t)E * 4);
  int*   offs   = (int*)alloc((size_t)(N + 1) * 4);
  int*   bsum   = (int*)alloc(4096);
  ushort_t* h1  = (ushort_t*)alloc(16384 * 2);
  ushort_t* l1  = (ushort_t*)alloc(16384 * 2);
  ushort_t* h2  = (ushort_t*)alloc(16384 * 2);
  ushort_t* l2  = (ushort_t*)alloc(16384 * 2);
  ushort_t* h3  = (ushort_t*)alloc(8192 * 2);
  ushort_t* l3  = (ushort_t*)alloc(8192 * 2);
  ushort_t* z1  = (ushort_t*)alloc((size_t)N * 128 * 2);  // bf16
  ushort_t* z2  = (ushort_t*)alloc((size_t)N * 128 * 2);  // bf16
  ushort_t* z3  = z1;                                     // reuse (N x 64 fits)

  int ge = (E + 255) / 256;
  int nb = (N + 1023) / 1024;

  hipMemsetAsync(cursor, 0, curBytes + 4, stream);
  k_detect<<<4, 256, 0, stream>>>((const int*)edges, flag, E);
  k_hist<<<ge, 256, 0, stream>>>(edges, flag, cursor, E);
  k_scan1<<<nb, 256, 0, stream>>>(cursor, offs, bsum, N);
  k_scan2<<<1, 128, 0, stream>>>(bsum, nb);
  k_scan3<<<nb, 256, 0, stream>>>(offs, bsum, cursor, N, E);
  k_fill<<<ge, 256, 0, stream>>>(edges, flag, cursor, csr, E);
  k_repack<<<160, 256, 0, stream>>>(W1, W2, W3, h1, l1, h2, l2, h3, l3);

  int gm = (N + 63) / 64;
  // layer 1: z1 = x @ W1   (bf16 out)
  k_gemm_mfma<128><<<gm, 256, 0, stream>>>(x, h1, l1, z1, N);
  // layer 2 fused: a1 = b1 + z1 + agg(z1) (regs); z2 = relu(a1) @ W2
  k_fused<128><<<gm, 256, 0, stream>>>(z1, csr, offs, b1, h2, l2, z2, N);
  // layer 3 fused: a2 = b2 + z2 + agg(z2) (regs); z3 = relu(a2) @ W3
  k_fused<64><<<gm, 256, 0, stream>>>(z2, csr, offs, b2, h3, l3, z3, N);
  // final agg: out = b3 + z3 + agg(z3)   (fp32 out)
  k_agg64<<<(N + 31) / 32, 256, 0, stream>>>(z3, csr, offs, b3, out, N);
}